// Round 9
// baseline (157.983 us; speedup 1.0000x reference)
//
#include <hip/hip_runtime.h>
#include <stdint.h>

#define T_STEPS  1000
#define BATCH    32
#define N_NEURON 1000
#define IN_DIM   128
#define OUT_DIM  20

typedef unsigned short ushort_t;
typedef unsigned long long ull_t;
using f32x4  = __attribute__((ext_vector_type(4))) float;
using bf16x8 = __attribute__((ext_vector_type(8))) short;

// fp32 -> bf16 (RTN-even)
static __device__ __forceinline__ ushort_t f2bf(float f) {
    unsigned u = __float_as_uint(f);
    return (ushort_t)((u + 0x7FFFu + ((u >> 16) & 1u)) >> 16);
}

// ws layout (bytes)
#define OFF_GMAX 0ull
#define WS_NEED  4ull

#define SIL_TH 14.5f   // spike needs w>=15; bf16-GEMM error ~0.06; actual max ~5.5

// ============================================================================
// Kernel 1: max-reduced bf16 MFMA GEMM — no stores, single pass over x.
// Silence proof: w_t = a_v*w_{t-1} + (1-a_v)*I_t (w = v-V_RESET, w0=0) is a
// convex combination of {0, past I}: w_max <= max(0, max I). Spike <=> w>=15.
// gmax = max over all (t,b,n) of in_scale*(x @ W_in^T); gmax < 14.5 => no
// spike ever, any batch => out = b_out exactly.
//
// Structure (fixes r8's 16-serial-B-load latency chain):
//   block = 1024 threads = 16 waves; wave w holds B-frags for 64 neurons
//   (4 n-tiles) in REGISTERS for the whole kernel, converted from fp32 W
//   (L2-resident) at start. 16 waves cover all 1024 padded neurons -> x is
//   read exactly once (grid = 250 blocks of 128 rows). x chunk staged in LDS
//   as bf16, stride 132 shorts (<=2-way bank aliasing = free); 8 m-tiles of
//   A-frags via ds_read_b128. MFMA: D row=quad*4+reg, col(N)=lane&15
//   (layout-blind anyway: max over all elements).
// ============================================================================
__global__ __launch_bounds__(1024, 4) void maxgemm_kernel(
    const float* __restrict__ x, const float* __restrict__ W,
    const float* __restrict__ in_scale_p, float* __restrict__ gmax)
{
    __shared__ ushort_t xs[128 * 132];   // 33792 B
    const int tid  = threadIdx.x;
    const int lane = tid & 63;
    const int wave = tid >> 6;
    const int quad = lane >> 4;
    const int l15  = lane & 15;
    const int m0   = blockIdx.x * 128;   // 250 * 128 = 32000 rows exactly
    const float is = in_scale_p[0];

    // ---- B-frags: fp32 W -> bf16 regs, once (rows >= 1000 zeroed) ----
    bf16x8 Bf[4][4];
    {
        const int n0 = wave * 64;
#pragma unroll
        for (int nt = 0; nt < 4; ++nt) {
            const int row = n0 + nt * 16 + l15;
            const bool ok = row < N_NEURON;
            const float* wp = W + (size_t)row * IN_DIM;
#pragma unroll
            for (int kb = 0; kb < 4; ++kb) {
                float4 lo = ok ? *(const float4*)(wp + kb * 32 + quad * 8)
                               : make_float4(0.f, 0.f, 0.f, 0.f);
                float4 hi = ok ? *(const float4*)(wp + kb * 32 + quad * 8 + 4)
                               : make_float4(0.f, 0.f, 0.f, 0.f);
                bf16x8 f;
                f[0] = (short)f2bf(lo.x); f[1] = (short)f2bf(lo.y);
                f[2] = (short)f2bf(lo.z); f[3] = (short)f2bf(lo.w);
                f[4] = (short)f2bf(hi.x); f[5] = (short)f2bf(hi.y);
                f[6] = (short)f2bf(hi.z); f[7] = (short)f2bf(hi.w);
                Bf[nt][kb] = f;
            }
        }
    }

    // ---- stage x[m0..m0+127][:] -> bf16 LDS (coalesced, conflict-free) ----
#pragma unroll
    for (int it = 0; it < 4; ++it) {
        int idx = tid + it * 1024;       // 0..4095 = 128 rows x 32 float4
        int row = idx >> 5, c4 = idx & 31;
        float4 v = *(const float4*)(x + (size_t)(m0 + row) * IN_DIM + c4 * 4);
        ushort_t* p = xs + row * 132 + c4 * 4;
        *(ushort4*)p = make_ushort4(f2bf(v.x), f2bf(v.y), f2bf(v.z), f2bf(v.w));
    }
    __syncthreads();

    // ---- 8 m-tiles x (4 n-tiles x 4 k-blocks) MFMAs, reduce to max ----
    float mx = 0.f;    // clamped >= 0 (bound uses max(0, I))
#pragma unroll
    for (int mt = 0; mt < 8; ++mt) {
        bf16x8 Af[4];
#pragma unroll
        for (int kb = 0; kb < 4; ++kb)
            Af[kb] = *(const bf16x8*)(xs + (mt * 16 + l15) * 132 +
                                      kb * 32 + quad * 8);
        f32x4 a0 = (f32x4){0.f, 0.f, 0.f, 0.f};
        f32x4 a1 = (f32x4){0.f, 0.f, 0.f, 0.f};
        f32x4 a2 = (f32x4){0.f, 0.f, 0.f, 0.f};
        f32x4 a3 = (f32x4){0.f, 0.f, 0.f, 0.f};
#pragma unroll
        for (int kb = 0; kb < 4; ++kb) {
            a0 = __builtin_amdgcn_mfma_f32_16x16x32_bf16(Af[kb], Bf[0][kb], a0, 0, 0, 0);
            a1 = __builtin_amdgcn_mfma_f32_16x16x32_bf16(Af[kb], Bf[1][kb], a1, 0, 0, 0);
            a2 = __builtin_amdgcn_mfma_f32_16x16x32_bf16(Af[kb], Bf[2][kb], a2, 0, 0, 0);
            a3 = __builtin_amdgcn_mfma_f32_16x16x32_bf16(Af[kb], Bf[3][kb], a3, 0, 0, 0);
        }
#pragma unroll
        for (int i = 0; i < 4; ++i) {
            mx = fmaxf(mx, is * a0[i]);
            mx = fmaxf(mx, is * a1[i]);
            mx = fmaxf(mx, is * a2[i]);
            mx = fmaxf(mx, is * a3[i]);
        }
    }

    // ---- lanes -> wave -> one device atomic (mx >= 0: int-bits monotone) ----
#pragma unroll
    for (int off = 32; off > 0; off >>= 1)
        mx = fmaxf(mx, __shfl_xor(mx, off, 64));
    if (lane == 0)
        atomicMax((int*)gmax, __float_as_int(mx));
}

// ============================================================================
// Kernel 2: gated full sequential sim (round-1 structure, known correct),
// with the resolve folded in: if gmax proves silence, write out = b_out
// bitwise and exit. gmax == nullptr (tiny-ws fallback) -> always run.
// ============================================================================
__global__ __launch_bounds__(256) void rsnn_seq_kernel(
    const float* __restrict__ gmax,
    const float* __restrict__ x,
    const float* __restrict__ W_in,
    const float* __restrict__ W_rec,
    const float* __restrict__ asc_amps,
    const float* __restrict__ k_decay,
    const float* __restrict__ W_out,
    const float* __restrict__ b_out,
    const float* __restrict__ in_scale_p,
    const float* __restrict__ out_scale_p,
    float* __restrict__ out)
{
    const int b   = blockIdx.x;
    const int tid = threadIdx.x;

    if (gmax && gmax[0] < SIL_TH) {      // silence proven for ALL batches
        if (tid < OUT_DIM) out[b * OUT_DIM + tid] = b_out[tid];
        return;
    }

    const int lane = tid & 63;
    const int wave = tid >> 6;
    const bool active = tid < (N_NEURON / 4);
    const int n0 = tid * 4;

    __shared__ ull_t smask[2][16];
    __shared__ float acc_sh[N_NEURON];
    __shared__ float xr[2][IN_DIM];

    const float a_v      = expf(-1.0f / 20.0f);
    const float a_syn    = expf(-1.0f / 5.0f);
    const float a_read   = expf(-1.0f / 20.0f);
    const float one_m_av = 1.0f - a_v;
    const float one_m_ar = 1.0f - a_read;
    const float VR = -60.0f, VTH = -45.0f;
    const float in_scale  = in_scale_p[0];
    const float out_scale = out_scale_p[0];

    float v[4], Ia[4], psc[4], f[4], acc[4], aasc[4], amp[4];
#pragma unroll
    for (int c = 0; c < 4; ++c) {
        v[c] = VR; Ia[c] = 0.f; psc[c] = 0.f; f[c] = 0.f; acc[c] = 0.f;
        aasc[c] = active ? expf(-k_decay[n0 + c]) : 0.f;
        amp[c]  = active ? asc_amps[n0 + c] : 0.f;
    }
    if (tid < 16) { smask[0][tid] = 0ull; smask[1][tid] = 0ull; }

    if (tid < IN_DIM / 4) {
        float4 xv = ((const float4*)(x + (size_t)b * IN_DIM))[tid];
        xr[0][tid * 4 + 0] = xv.x * in_scale; xr[0][tid * 4 + 1] = xv.y * in_scale;
        xr[0][tid * 4 + 2] = xv.z * in_scale; xr[0][tid * 4 + 3] = xv.w * in_scale;
    }
    int prev_any = 0;
    __syncthreads();

    for (int t = 0; t < T_STEPS; ++t) {
        const int cur = t & 1, nxt = cur ^ 1;
        if (t + 1 < T_STEPS && tid < IN_DIM / 4) {
            float4 xv = ((const float4*)(x + (size_t)((t + 1) * BATCH + b) * IN_DIM))[tid];
            xr[nxt][tid * 4 + 0] = xv.x * in_scale; xr[nxt][tid * 4 + 1] = xv.y * in_scale;
            xr[nxt][tid * 4 + 2] = xv.z * in_scale; xr[nxt][tid * 4 + 3] = xv.w * in_scale;
        }
        float4 Icur = make_float4(0.f, 0.f, 0.f, 0.f);
        if (active) {
            float s0 = 0.f, s1 = 0.f, s2 = 0.f, s3 = 0.f;
            const float4* w0 = (const float4*)(W_in + (size_t)(n0 + 0) * IN_DIM);
            const float4* w1 = (const float4*)(W_in + (size_t)(n0 + 1) * IN_DIM);
            const float4* w2 = (const float4*)(W_in + (size_t)(n0 + 2) * IN_DIM);
            const float4* w3 = (const float4*)(W_in + (size_t)(n0 + 3) * IN_DIM);
#pragma unroll 8
            for (int k4 = 0; k4 < IN_DIM / 4; ++k4) {
                float4 xv = *((const float4*)&xr[cur][0] + k4);
                float4 a0 = w0[k4], a1 = w1[k4], a2 = w2[k4], a3 = w3[k4];
                s0 += xv.x * a0.x + xv.y * a0.y + xv.z * a0.z + xv.w * a0.w;
                s1 += xv.x * a1.x + xv.y * a1.y + xv.z * a1.z + xv.w * a1.w;
                s2 += xv.x * a2.x + xv.y * a2.y + xv.z * a2.z + xv.w * a2.w;
                s3 += xv.x * a3.x + xv.y * a3.y + xv.z * a3.z + xv.w * a3.w;
            }
            Icur = make_float4(s0, s1, s2, s3);
        }

#pragma unroll
        for (int c = 0; c < 4; ++c) psc[c] *= a_syn;
        if (prev_any && active) {
#pragma unroll 1
            for (int w = 0; w < 16; ++w) {
                ull_t m = smask[nxt][w];
                while (m) {
                    int bit = __ffsll(m) - 1;
                    m &= m - 1;
                    int npre = ((w >> 2) << 8) + (bit << 2) + (w & 3);
                    const float4 wr = *(const float4*)(W_rec + (size_t)npre * N_NEURON + n0);
                    psc[0] += wr.x; psc[1] += wr.y; psc[2] += wr.z; psc[3] += wr.w;
                }
            }
        }

        float Iv[4] = {Icur.x, Icur.y, Icur.z, Icur.w};
        bool sp[4];
#pragma unroll
        for (int c = 0; c < 4; ++c) {
            float It = Iv[c] + psc[c] + Ia[c];
            float vn = VR + a_v * (v[c] - VR) + one_m_av * It;
            bool s = active && (vn - VTH >= 0.0f);
            float sf = s ? 1.0f : 0.0f;
            vn = vn - (vn - VR) * sf;
            v[c] = vn;
            Ia[c] = aasc[c] * Ia[c] + amp[c] * sf;
            f[c] = (t == 0) ? sf : (a_read * f[c] + one_m_ar * sf);
            if (t >= 199) acc[c] += f[c];
            sp[c] = s;
        }

#pragma unroll
        for (int c = 0; c < 4; ++c) {
            ull_t m = __ballot(sp[c]);
            if (lane == 0) smask[cur][wave * 4 + c] = m;
        }
        int myany = (sp[0] | sp[1] | sp[2] | sp[3]) ? 1 : 0;
        prev_any = __syncthreads_or(myany);
    }

    if (active) {
        acc_sh[n0 + 0] = acc[0]; acc_sh[n0 + 1] = acc[1];
        acc_sh[n0 + 2] = acc[2]; acc_sh[n0 + 3] = acc[3];
    }
    __syncthreads();

    const float inv_cnt = 1.0f / 801.0f;
#pragma unroll
    for (int oo = 0; oo < 5; ++oo) {
        int o = wave * 5 + oo;
        float p = 0.f;
        for (int n = lane; n < N_NEURON; n += 64)
            p += acc_sh[n] * W_out[(size_t)o * N_NEURON + n];
#pragma unroll
        for (int off = 32; off > 0; off >>= 1)
            p += __shfl_down(p, off, 64);
        if (lane == 0)
            out[b * OUT_DIM + o] = out_scale * (p * inv_cnt) + b_out[o];
    }
}

// ============================================================================
extern "C" void kernel_launch(void* const* d_in, const int* in_sizes, int n_in,
                              void* d_out, int out_size, void* d_ws, size_t ws_size,
                              hipStream_t stream)
{
    const float* x         = (const float*)d_in[0];
    const float* W_in      = (const float*)d_in[1];
    const float* W_rec     = (const float*)d_in[2];
    const float* asc_amps  = (const float*)d_in[3];
    const float* k_decay   = (const float*)d_in[4];
    const float* W_out     = (const float*)d_in[5];
    const float* b_out     = (const float*)d_in[6];
    const float* in_scale  = (const float*)d_in[7];
    const float* out_scale = (const float*)d_in[8];
    float* out = (float*)d_out;

    if (ws_size >= WS_NEED) {
        float* gmax = (float*)((char*)d_ws + OFF_GMAX);
        hipMemsetAsync(gmax, 0, sizeof(float), stream);   // graph-capturable
        maxgemm_kernel<<<250, 1024, 0, stream>>>(x, W_in, in_scale, gmax);
        rsnn_seq_kernel<<<BATCH, 256, 0, stream>>>(
            gmax, x, W_in, W_rec, asc_amps, k_decay, W_out, b_out,
            in_scale, out_scale, out);
    } else {
        rsnn_seq_kernel<<<BATCH, 256, 0, stream>>>(
            nullptr, x, W_in, W_rec, asc_amps, k_decay, W_out, b_out,
            in_scale, out_scale, out);
    }
}

// Round 10
// 140.719 us; speedup vs baseline: 1.1227x; 1.1227x over previous
//
#include <hip/hip_runtime.h>
#include <stdint.h>

#define T_STEPS  1000
#define BATCH    32
#define N_NEURON 1000
#define IN_DIM   128
#define OUT_DIM  20

typedef unsigned short ushort_t;
typedef unsigned long long ull_t;
using f32x4  = __attribute__((ext_vector_type(4))) float;
using bf16x8 = __attribute__((ext_vector_type(8))) short;

// fp32 -> bf16 (RTN-even)
static __device__ __forceinline__ ushort_t f2bf(float f) {
    unsigned u = __float_as_uint(f);
    return (ushort_t)((u + 0x7FFFu + ((u >> 16) & 1u)) >> 16);
}

// ws layout (bytes)
#define OFF_GMAX 0ull
#define WS_NEED  4ull

#define SIL_TH 14.5f   // spike needs w>=15; bf16-GEMM error ~0.06; actual max ~5.5

// ============================================================================
// Kernel 1: max-reduced bf16 MFMA GEMM — no stores.
// Silence proof: w_t = a_v*w_{t-1} + (1-a_v)*I_t (w = v-V_RESET, w0=0) is a
// convex combination of {0, past I}: w_max <= max(0, max I). Spike <=> w>=15.
// gmax = max over all (t,b,n) of in_scale*(x @ W_in^T); gmax < 14.5 => no
// spike ever, any batch => out = b_out exactly (avg filtered == 0).
//
// r9 post-mortem fix: 1024-thread block + launch_bounds(1024,4) capped the
// allocator at 64 VGPRs -> B-fragments spilled to scratch (47 MB HBM writes).
// v3: 256-thread blocks, launch_bounds(256,1) (up to 512 VGPRs -> no spill).
// Wave holds Bf for its 64 neurons in REGISTERS for the whole kernel
// (converted once from fp32 W, L2/L3-resident). x slab staged once per block
// into bf16 LDS (stride 132 shorts: <=2-way aliasing = free); inner loop is
// pure ds_read_b128 + MFMA. Grid (250, 4): x re-read across grid.y served
// mostly by L3. Max is invariant to MFMA fragment layout -> layout-proof.
// ============================================================================
__global__ __launch_bounds__(256, 1) void maxgemm_kernel(
    const float* __restrict__ x, const float* __restrict__ W,
    const float* __restrict__ in_scale_p, float* __restrict__ gmax)
{
    __shared__ ushort_t xs[128 * 132];   // 33792 B
    const int tid  = threadIdx.x;
    const int lane = tid & 63;
    const int wave = tid >> 6;
    const int quad = lane >> 4;
    const int l15  = lane & 15;
    const int m0   = blockIdx.x * 128;           // 250 * 128 = 32000 rows
    const int n0   = blockIdx.y * 256 + wave * 64;  // padded 1024 neurons
    const float is = in_scale_p[0];

    // ---- B-frags: fp32 W -> bf16 regs, once (rows >= 1000 zeroed) ----
    bf16x8 Bf[4][4];
#pragma unroll
    for (int nt = 0; nt < 4; ++nt) {
        const int row = n0 + nt * 16 + l15;
        const bool ok = row < N_NEURON;
        const float* wp = W + (size_t)row * IN_DIM;
#pragma unroll
        for (int kb = 0; kb < 4; ++kb) {
            float4 lo = ok ? *(const float4*)(wp + kb * 32 + quad * 8)
                           : make_float4(0.f, 0.f, 0.f, 0.f);
            float4 hi = ok ? *(const float4*)(wp + kb * 32 + quad * 8 + 4)
                           : make_float4(0.f, 0.f, 0.f, 0.f);
            bf16x8 f;
            f[0] = (short)f2bf(lo.x); f[1] = (short)f2bf(lo.y);
            f[2] = (short)f2bf(lo.z); f[3] = (short)f2bf(lo.w);
            f[4] = (short)f2bf(hi.x); f[5] = (short)f2bf(hi.y);
            f[6] = (short)f2bf(hi.z); f[7] = (short)f2bf(hi.w);
            Bf[nt][kb] = f;
        }
    }

    // ---- stage x[m0..m0+127][:] -> bf16 LDS (coalesced, conflict-free) ----
#pragma unroll
    for (int it = 0; it < 16; ++it) {
        int idx = tid + it * 256;        // 0..4095 = 128 rows x 32 float4
        int row = idx >> 5, c4 = idx & 31;
        float4 v = *(const float4*)(x + (size_t)(m0 + row) * IN_DIM + c4 * 4);
        ushort_t* p = xs + row * 132 + c4 * 4;
        *(ushort4*)p = make_ushort4(f2bf(v.x), f2bf(v.y), f2bf(v.z), f2bf(v.w));
    }
    __syncthreads();

    // ---- 8 m-tiles x (4 n-tiles x 4 k-blocks) MFMAs, reduce to max ----
    float mx = 0.f;    // clamped >= 0 (bound uses max(0, I))
#pragma unroll
    for (int mt = 0; mt < 8; ++mt) {
        bf16x8 Af[4];
#pragma unroll
        for (int kb = 0; kb < 4; ++kb)
            Af[kb] = *(const bf16x8*)(xs + (mt * 16 + l15) * 132 +
                                      kb * 32 + quad * 8);
        f32x4 a0 = (f32x4){0.f, 0.f, 0.f, 0.f};
        f32x4 a1 = (f32x4){0.f, 0.f, 0.f, 0.f};
        f32x4 a2 = (f32x4){0.f, 0.f, 0.f, 0.f};
        f32x4 a3 = (f32x4){0.f, 0.f, 0.f, 0.f};
#pragma unroll
        for (int kb = 0; kb < 4; ++kb) {
            a0 = __builtin_amdgcn_mfma_f32_16x16x32_bf16(Af[kb], Bf[0][kb], a0, 0, 0, 0);
            a1 = __builtin_amdgcn_mfma_f32_16x16x32_bf16(Af[kb], Bf[1][kb], a1, 0, 0, 0);
            a2 = __builtin_amdgcn_mfma_f32_16x16x32_bf16(Af[kb], Bf[2][kb], a2, 0, 0, 0);
            a3 = __builtin_amdgcn_mfma_f32_16x16x32_bf16(Af[kb], Bf[3][kb], a3, 0, 0, 0);
        }
#pragma unroll
        for (int i = 0; i < 4; ++i) {
            mx = fmaxf(mx, is * a0[i]);
            mx = fmaxf(mx, is * a1[i]);
            mx = fmaxf(mx, is * a2[i]);
            mx = fmaxf(mx, is * a3[i]);
        }
    }

    // ---- lanes -> wave -> one device atomic (mx >= 0: int-bits monotone) ----
#pragma unroll
    for (int off = 32; off > 0; off >>= 1)
        mx = fmaxf(mx, __shfl_xor(mx, off, 64));
    if (lane == 0)
        atomicMax((int*)gmax, __float_as_int(mx));
}

// ============================================================================
// Kernel 2: gated full sequential sim (round-1 structure, known correct),
// with the resolve folded in: if gmax proves silence, write out = b_out
// bitwise and exit. gmax == nullptr (tiny-ws fallback) -> always run.
// ============================================================================
__global__ __launch_bounds__(256) void rsnn_seq_kernel(
    const float* __restrict__ gmax,
    const float* __restrict__ x,
    const float* __restrict__ W_in,
    const float* __restrict__ W_rec,
    const float* __restrict__ asc_amps,
    const float* __restrict__ k_decay,
    const float* __restrict__ W_out,
    const float* __restrict__ b_out,
    const float* __restrict__ in_scale_p,
    const float* __restrict__ out_scale_p,
    float* __restrict__ out)
{
    const int b   = blockIdx.x;
    const int tid = threadIdx.x;

    if (gmax && gmax[0] < SIL_TH) {      // silence proven for ALL batches
        if (tid < OUT_DIM) out[b * OUT_DIM + tid] = b_out[tid];
        return;
    }

    const int lane = tid & 63;
    const int wave = tid >> 6;
    const bool active = tid < (N_NEURON / 4);
    const int n0 = tid * 4;

    __shared__ ull_t smask[2][16];
    __shared__ float acc_sh[N_NEURON];
    __shared__ float xr[2][IN_DIM];

    const float a_v      = expf(-1.0f / 20.0f);
    const float a_syn    = expf(-1.0f / 5.0f);
    const float a_read   = expf(-1.0f / 20.0f);
    const float one_m_av = 1.0f - a_v;
    const float one_m_ar = 1.0f - a_read;
    const float VR = -60.0f, VTH = -45.0f;
    const float in_scale  = in_scale_p[0];
    const float out_scale = out_scale_p[0];

    float v[4], Ia[4], psc[4], f[4], acc[4], aasc[4], amp[4];
#pragma unroll
    for (int c = 0; c < 4; ++c) {
        v[c] = VR; Ia[c] = 0.f; psc[c] = 0.f; f[c] = 0.f; acc[c] = 0.f;
        aasc[c] = active ? expf(-k_decay[n0 + c]) : 0.f;
        amp[c]  = active ? asc_amps[n0 + c] : 0.f;
    }
    if (tid < 16) { smask[0][tid] = 0ull; smask[1][tid] = 0ull; }

    if (tid < IN_DIM / 4) {
        float4 xv = ((const float4*)(x + (size_t)b * IN_DIM))[tid];
        xr[0][tid * 4 + 0] = xv.x * in_scale; xr[0][tid * 4 + 1] = xv.y * in_scale;
        xr[0][tid * 4 + 2] = xv.z * in_scale; xr[0][tid * 4 + 3] = xv.w * in_scale;
    }
    int prev_any = 0;
    __syncthreads();

    for (int t = 0; t < T_STEPS; ++t) {
        const int cur = t & 1, nxt = cur ^ 1;
        if (t + 1 < T_STEPS && tid < IN_DIM / 4) {
            float4 xv = ((const float4*)(x + (size_t)((t + 1) * BATCH + b) * IN_DIM))[tid];
            xr[nxt][tid * 4 + 0] = xv.x * in_scale; xr[nxt][tid * 4 + 1] = xv.y * in_scale;
            xr[nxt][tid * 4 + 2] = xv.z * in_scale; xr[nxt][tid * 4 + 3] = xv.w * in_scale;
        }
        float4 Icur = make_float4(0.f, 0.f, 0.f, 0.f);
        if (active) {
            float s0 = 0.f, s1 = 0.f, s2 = 0.f, s3 = 0.f;
            const float4* w0 = (const float4*)(W_in + (size_t)(n0 + 0) * IN_DIM);
            const float4* w1 = (const float4*)(W_in + (size_t)(n0 + 1) * IN_DIM);
            const float4* w2 = (const float4*)(W_in + (size_t)(n0 + 2) * IN_DIM);
            const float4* w3 = (const float4*)(W_in + (size_t)(n0 + 3) * IN_DIM);
#pragma unroll 8
            for (int k4 = 0; k4 < IN_DIM / 4; ++k4) {
                float4 xv = *((const float4*)&xr[cur][0] + k4);
                float4 a0 = w0[k4], a1 = w1[k4], a2 = w2[k4], a3 = w3[k4];
                s0 += xv.x * a0.x + xv.y * a0.y + xv.z * a0.z + xv.w * a0.w;
                s1 += xv.x * a1.x + xv.y * a1.y + xv.z * a1.z + xv.w * a1.w;
                s2 += xv.x * a2.x + xv.y * a2.y + xv.z * a2.z + xv.w * a2.w;
                s3 += xv.x * a3.x + xv.y * a3.y + xv.z * a3.z + xv.w * a3.w;
            }
            Icur = make_float4(s0, s1, s2, s3);
        }

#pragma unroll
        for (int c = 0; c < 4; ++c) psc[c] *= a_syn;
        if (prev_any && active) {
#pragma unroll 1
            for (int w = 0; w < 16; ++w) {
                ull_t m = smask[nxt][w];
                while (m) {
                    int bit = __ffsll(m) - 1;
                    m &= m - 1;
                    int npre = ((w >> 2) << 8) + (bit << 2) + (w & 3);
                    const float4 wr = *(const float4*)(W_rec + (size_t)npre * N_NEURON + n0);
                    psc[0] += wr.x; psc[1] += wr.y; psc[2] += wr.z; psc[3] += wr.w;
                }
            }
        }

        float Iv[4] = {Icur.x, Icur.y, Icur.z, Icur.w};
        bool sp[4];
#pragma unroll
        for (int c = 0; c < 4; ++c) {
            float It = Iv[c] + psc[c] + Ia[c];
            float vn = VR + a_v * (v[c] - VR) + one_m_av * It;
            bool s = active && (vn - VTH >= 0.0f);
            float sf = s ? 1.0f : 0.0f;
            vn = vn - (vn - VR) * sf;
            v[c] = vn;
            Ia[c] = aasc[c] * Ia[c] + amp[c] * sf;
            f[c] = (t == 0) ? sf : (a_read * f[c] + one_m_ar * sf);
            if (t >= 199) acc[c] += f[c];
            sp[c] = s;
        }

#pragma unroll
        for (int c = 0; c < 4; ++c) {
            ull_t m = __ballot(sp[c]);
            if (lane == 0) smask[cur][wave * 4 + c] = m;
        }
        int myany = (sp[0] | sp[1] | sp[2] | sp[3]) ? 1 : 0;
        prev_any = __syncthreads_or(myany);
    }

    if (active) {
        acc_sh[n0 + 0] = acc[0]; acc_sh[n0 + 1] = acc[1];
        acc_sh[n0 + 2] = acc[2]; acc_sh[n0 + 3] = acc[3];
    }
    __syncthreads();

    const float inv_cnt = 1.0f / 801.0f;
#pragma unroll
    for (int oo = 0; oo < 5; ++oo) {
        int o = wave * 5 + oo;
        float p = 0.f;
        for (int n = lane; n < N_NEURON; n += 64)
            p += acc_sh[n] * W_out[(size_t)o * N_NEURON + n];
#pragma unroll
        for (int off = 32; off > 0; off >>= 1)
            p += __shfl_down(p, off, 64);
        if (lane == 0)
            out[b * OUT_DIM + o] = out_scale * (p * inv_cnt) + b_out[o];
    }
}

// ============================================================================
extern "C" void kernel_launch(void* const* d_in, const int* in_sizes, int n_in,
                              void* d_out, int out_size, void* d_ws, size_t ws_size,
                              hipStream_t stream)
{
    const float* x         = (const float*)d_in[0];
    const float* W_in      = (const float*)d_in[1];
    const float* W_rec     = (const float*)d_in[2];
    const float* asc_amps  = (const float*)d_in[3];
    const float* k_decay   = (const float*)d_in[4];
    const float* W_out     = (const float*)d_in[5];
    const float* b_out     = (const float*)d_in[6];
    const float* in_scale  = (const float*)d_in[7];
    const float* out_scale = (const float*)d_in[8];
    float* out = (float*)d_out;

    if (ws_size >= WS_NEED) {
        float* gmax = (float*)((char*)d_ws + OFF_GMAX);
        hipMemsetAsync(gmax, 0, sizeof(float), stream);   // graph-capturable
        maxgemm_kernel<<<dim3(250, 4), 256, 0, stream>>>(x, W_in, in_scale, gmax);
        rsnn_seq_kernel<<<BATCH, 256, 0, stream>>>(
            gmax, x, W_in, W_rec, asc_amps, k_decay, W_out, b_out,
            in_scale, out_scale, out);
    } else {
        rsnn_seq_kernel<<<BATCH, 256, 0, stream>>>(
            nullptr, x, W_in, W_rec, asc_amps, k_decay, W_out, b_out,
            in_scale, out_scale, out);
    }
}

// Round 11
// 112.618 us; speedup vs baseline: 1.4028x; 1.2495x over previous
//
#include <hip/hip_runtime.h>
#include <stdint.h>

#define T_STEPS  1000
#define BATCH    32
#define N_NEURON 1000
#define IN_DIM   128
#define OUT_DIM  20

typedef unsigned short ushort_t;
typedef unsigned long long ull_t;
using f32x4  = __attribute__((ext_vector_type(4))) float;
using bf16x8 = __attribute__((ext_vector_type(8))) short;

// fp32 -> bf16 (RTN-even)
static __device__ __forceinline__ ushort_t f2bf(float f) {
    unsigned u = __float_as_uint(f);
    return (ushort_t)((u + 0x7FFFu + ((u >> 16) & 1u)) >> 16);
}

// ws layout (bytes): 1024 per-block maxima (1000 used, rest stay 0 via memset)
#define OFF_GMAXA 0ull
#define GMAXA_N   1024
#define WS_NEED   (GMAXA_N * 4ull)

#define SIL_TH 14.5f   // spike needs w>=15; bf16-GEMM error ~0.06; actual max ~5.5

// ============================================================================
// Kernel 1: max-reduced bf16 MFMA GEMM — no stores except ONE per block.
// Silence proof: w_t = a_v*w_{t-1} + (1-a_v)*I_t (w = v-V_RESET, w0=0) is a
// convex combination of {0, past I}: w_max <= max(0, max I). Spike <=> w>=15.
// gmax = max over all (t,b,n) of in_scale*(x @ W_in^T); gmax < 14.5 => no
// spike ever, any batch => out = b_out exactly (avg filtered == 0).
//
// r10 post-mortem fix: 4000 wave-atomicMax to ONE address serialized at
// ~40 cy each = the whole 67 µs (L3-warm replays took the same 66 µs ->
// traffic-independent; WRITE_SIZE 125 KB = 4000x32B RMWs). v4: cross-wave
// LDS reduce -> ONE plain store per block into a disjoint slot (no atomics).
// GEMM structure unchanged from v3 (no spill: VGPR 88; B-frags in regs,
// x slab in bf16 LDS stride 132 = <=2-way free aliasing).
// ============================================================================
__global__ __launch_bounds__(256, 1) void maxgemm_kernel(
    const float* __restrict__ x, const float* __restrict__ W,
    const float* __restrict__ in_scale_p, float* __restrict__ gmaxa)
{
    __shared__ ushort_t xs[128 * 132];   // 33792 B
    __shared__ float wred[4];
    const int tid  = threadIdx.x;
    const int lane = tid & 63;
    const int wave = tid >> 6;
    const int quad = lane >> 4;
    const int l15  = lane & 15;
    const int m0   = blockIdx.x * 128;              // 250 * 128 = 32000 rows
    const int n0   = blockIdx.y * 256 + wave * 64;  // padded 1024 neurons
    const float is = in_scale_p[0];

    // ---- B-frags: fp32 W -> bf16 regs, once (rows >= 1000 zeroed) ----
    bf16x8 Bf[4][4];
#pragma unroll
    for (int nt = 0; nt < 4; ++nt) {
        const int row = n0 + nt * 16 + l15;
        const bool ok = row < N_NEURON;
        const float* wp = W + (size_t)row * IN_DIM;
#pragma unroll
        for (int kb = 0; kb < 4; ++kb) {
            float4 lo = ok ? *(const float4*)(wp + kb * 32 + quad * 8)
                           : make_float4(0.f, 0.f, 0.f, 0.f);
            float4 hi = ok ? *(const float4*)(wp + kb * 32 + quad * 8 + 4)
                           : make_float4(0.f, 0.f, 0.f, 0.f);
            bf16x8 f;
            f[0] = (short)f2bf(lo.x); f[1] = (short)f2bf(lo.y);
            f[2] = (short)f2bf(lo.z); f[3] = (short)f2bf(lo.w);
            f[4] = (short)f2bf(hi.x); f[5] = (short)f2bf(hi.y);
            f[6] = (short)f2bf(hi.z); f[7] = (short)f2bf(hi.w);
            Bf[nt][kb] = f;
        }
    }

    // ---- stage x[m0..m0+127][:] -> bf16 LDS (coalesced, conflict-free) ----
#pragma unroll
    for (int it = 0; it < 16; ++it) {
        int idx = tid + it * 256;        // 0..4095 = 128 rows x 32 float4
        int row = idx >> 5, c4 = idx & 31;
        float4 v = *(const float4*)(x + (size_t)(m0 + row) * IN_DIM + c4 * 4);
        ushort_t* p = xs + row * 132 + c4 * 4;
        *(ushort4*)p = make_ushort4(f2bf(v.x), f2bf(v.y), f2bf(v.z), f2bf(v.w));
    }
    __syncthreads();

    // ---- 8 m-tiles x (4 n-tiles x 4 k-blocks) MFMAs, reduce to max ----
    float mx = 0.f;    // clamped >= 0 (bound uses max(0, I))
#pragma unroll
    for (int mt = 0; mt < 8; ++mt) {
        bf16x8 Af[4];
#pragma unroll
        for (int kb = 0; kb < 4; ++kb)
            Af[kb] = *(const bf16x8*)(xs + (mt * 16 + l15) * 132 +
                                      kb * 32 + quad * 8);
        f32x4 a0 = (f32x4){0.f, 0.f, 0.f, 0.f};
        f32x4 a1 = (f32x4){0.f, 0.f, 0.f, 0.f};
        f32x4 a2 = (f32x4){0.f, 0.f, 0.f, 0.f};
        f32x4 a3 = (f32x4){0.f, 0.f, 0.f, 0.f};
#pragma unroll
        for (int kb = 0; kb < 4; ++kb) {
            a0 = __builtin_amdgcn_mfma_f32_16x16x32_bf16(Af[kb], Bf[0][kb], a0, 0, 0, 0);
            a1 = __builtin_amdgcn_mfma_f32_16x16x32_bf16(Af[kb], Bf[1][kb], a1, 0, 0, 0);
            a2 = __builtin_amdgcn_mfma_f32_16x16x32_bf16(Af[kb], Bf[2][kb], a2, 0, 0, 0);
            a3 = __builtin_amdgcn_mfma_f32_16x16x32_bf16(Af[kb], Bf[3][kb], a3, 0, 0, 0);
        }
#pragma unroll
        for (int i = 0; i < 4; ++i) {
            mx = fmaxf(mx, is * a0[i]);
            mx = fmaxf(mx, is * a1[i]);
            mx = fmaxf(mx, is * a2[i]);
            mx = fmaxf(mx, is * a3[i]);
        }
    }

    // ---- lanes -> wave -> block (LDS) -> ONE plain store, no atomics ----
#pragma unroll
    for (int off = 32; off > 0; off >>= 1)
        mx = fmaxf(mx, __shfl_xor(mx, off, 64));
    if (lane == 0) wred[wave] = mx;
    __syncthreads();
    if (tid == 0) {
        float bm = fmaxf(fmaxf(wred[0], wred[1]), fmaxf(wred[2], wred[3]));
        gmaxa[blockIdx.y * 250 + blockIdx.x] = bm;   // disjoint slot per block
    }
}

// ============================================================================
// Kernel 2: gated full sequential sim (round-1 structure, known correct),
// with the resolve folded in: each block scans the 1024-entry per-block-max
// array (1000 valid + memset-zero pad); if silence is proven, write
// out = b_out bitwise and exit. gmaxa == nullptr (tiny-ws) -> always run.
// ============================================================================
__global__ __launch_bounds__(256) void rsnn_seq_kernel(
    const float* __restrict__ gmaxa,
    const float* __restrict__ x,
    const float* __restrict__ W_in,
    const float* __restrict__ W_rec,
    const float* __restrict__ asc_amps,
    const float* __restrict__ k_decay,
    const float* __restrict__ W_out,
    const float* __restrict__ b_out,
    const float* __restrict__ in_scale_p,
    const float* __restrict__ out_scale_p,
    float* __restrict__ out)
{
    const int b   = blockIdx.x;
    const int tid = threadIdx.x;

    if (gmaxa) {
        float4 g = *(const float4*)(gmaxa + tid * 4);   // 1024 = 256 x 4
        bool trig = (g.x >= SIL_TH) || (g.y >= SIL_TH) ||
                    (g.z >= SIL_TH) || (g.w >= SIL_TH);
        int any = __syncthreads_or(trig ? 1 : 0);       // block-uniform
        if (any == 0) {                                 // silence proven
            if (tid < OUT_DIM) out[b * OUT_DIM + tid] = b_out[tid];
            return;
        }
    }

    const int lane = tid & 63;
    const int wave = tid >> 6;
    const bool active = tid < (N_NEURON / 4);
    const int n0 = tid * 4;

    __shared__ ull_t smask[2][16];
    __shared__ float acc_sh[N_NEURON];
    __shared__ float xr[2][IN_DIM];

    const float a_v      = expf(-1.0f / 20.0f);
    const float a_syn    = expf(-1.0f / 5.0f);
    const float a_read   = expf(-1.0f / 20.0f);
    const float one_m_av = 1.0f - a_v;
    const float one_m_ar = 1.0f - a_read;
    const float VR = -60.0f, VTH = -45.0f;
    const float in_scale  = in_scale_p[0];
    const float out_scale = out_scale_p[0];

    float v[4], Ia[4], psc[4], f[4], acc[4], aasc[4], amp[4];
#pragma unroll
    for (int c = 0; c < 4; ++c) {
        v[c] = VR; Ia[c] = 0.f; psc[c] = 0.f; f[c] = 0.f; acc[c] = 0.f;
        aasc[c] = active ? expf(-k_decay[n0 + c]) : 0.f;
        amp[c]  = active ? asc_amps[n0 + c] : 0.f;
    }
    if (tid < 16) { smask[0][tid] = 0ull; smask[1][tid] = 0ull; }

    if (tid < IN_DIM / 4) {
        float4 xv = ((const float4*)(x + (size_t)b * IN_DIM))[tid];
        xr[0][tid * 4 + 0] = xv.x * in_scale; xr[0][tid * 4 + 1] = xv.y * in_scale;
        xr[0][tid * 4 + 2] = xv.z * in_scale; xr[0][tid * 4 + 3] = xv.w * in_scale;
    }
    int prev_any = 0;
    __syncthreads();

    for (int t = 0; t < T_STEPS; ++t) {
        const int cur = t & 1, nxt = cur ^ 1;
        if (t + 1 < T_STEPS && tid < IN_DIM / 4) {
            float4 xv = ((const float4*)(x + (size_t)((t + 1) * BATCH + b) * IN_DIM))[tid];
            xr[nxt][tid * 4 + 0] = xv.x * in_scale; xr[nxt][tid * 4 + 1] = xv.y * in_scale;
            xr[nxt][tid * 4 + 2] = xv.z * in_scale; xr[nxt][tid * 4 + 3] = xv.w * in_scale;
        }
        float4 Icur = make_float4(0.f, 0.f, 0.f, 0.f);
        if (active) {
            float s0 = 0.f, s1 = 0.f, s2 = 0.f, s3 = 0.f;
            const float4* w0 = (const float4*)(W_in + (size_t)(n0 + 0) * IN_DIM);
            const float4* w1 = (const float4*)(W_in + (size_t)(n0 + 1) * IN_DIM);
            const float4* w2 = (const float4*)(W_in + (size_t)(n0 + 2) * IN_DIM);
            const float4* w3 = (const float4*)(W_in + (size_t)(n0 + 3) * IN_DIM);
#pragma unroll 8
            for (int k4 = 0; k4 < IN_DIM / 4; ++k4) {
                float4 xv = *((const float4*)&xr[cur][0] + k4);
                float4 a0 = w0[k4], a1 = w1[k4], a2 = w2[k4], a3 = w3[k4];
                s0 += xv.x * a0.x + xv.y * a0.y + xv.z * a0.z + xv.w * a0.w;
                s1 += xv.x * a1.x + xv.y * a1.y + xv.z * a1.z + xv.w * a1.w;
                s2 += xv.x * a2.x + xv.y * a2.y + xv.z * a2.z + xv.w * a2.w;
                s3 += xv.x * a3.x + xv.y * a3.y + xv.z * a3.z + xv.w * a3.w;
            }
            Icur = make_float4(s0, s1, s2, s3);
        }

#pragma unroll
        for (int c = 0; c < 4; ++c) psc[c] *= a_syn;
        if (prev_any && active) {
#pragma unroll 1
            for (int w = 0; w < 16; ++w) {
                ull_t m = smask[nxt][w];
                while (m) {
                    int bit = __ffsll(m) - 1;
                    m &= m - 1;
                    int npre = ((w >> 2) << 8) + (bit << 2) + (w & 3);
                    const float4 wr = *(const float4*)(W_rec + (size_t)npre * N_NEURON + n0);
                    psc[0] += wr.x; psc[1] += wr.y; psc[2] += wr.z; psc[3] += wr.w;
                }
            }
        }

        float Iv[4] = {Icur.x, Icur.y, Icur.z, Icur.w};
        bool sp[4];
#pragma unroll
        for (int c = 0; c < 4; ++c) {
            float It = Iv[c] + psc[c] + Ia[c];
            float vn = VR + a_v * (v[c] - VR) + one_m_av * It;
            bool s = active && (vn - VTH >= 0.0f);
            float sf = s ? 1.0f : 0.0f;
            vn = vn - (vn - VR) * sf;
            v[c] = vn;
            Ia[c] = aasc[c] * Ia[c] + amp[c] * sf;
            f[c] = (t == 0) ? sf : (a_read * f[c] + one_m_ar * sf);
            if (t >= 199) acc[c] += f[c];
            sp[c] = s;
        }

#pragma unroll
        for (int c = 0; c < 4; ++c) {
            ull_t m = __ballot(sp[c]);
            if (lane == 0) smask[cur][wave * 4 + c] = m;
        }
        int myany = (sp[0] | sp[1] | sp[2] | sp[3]) ? 1 : 0;
        prev_any = __syncthreads_or(myany);
    }

    if (active) {
        acc_sh[n0 + 0] = acc[0]; acc_sh[n0 + 1] = acc[1];
        acc_sh[n0 + 2] = acc[2]; acc_sh[n0 + 3] = acc[3];
    }
    __syncthreads();

    const float inv_cnt = 1.0f / 801.0f;
#pragma unroll
    for (int oo = 0; oo < 5; ++oo) {
        int o = wave * 5 + oo;
        float p = 0.f;
        for (int n = lane; n < N_NEURON; n += 64)
            p += acc_sh[n] * W_out[(size_t)o * N_NEURON + n];
#pragma unroll
        for (int off = 32; off > 0; off >>= 1)
            p += __shfl_down(p, off, 64);
        if (lane == 0)
            out[b * OUT_DIM + o] = out_scale * (p * inv_cnt) + b_out[o];
    }
}

// ============================================================================
extern "C" void kernel_launch(void* const* d_in, const int* in_sizes, int n_in,
                              void* d_out, int out_size, void* d_ws, size_t ws_size,
                              hipStream_t stream)
{
    const float* x         = (const float*)d_in[0];
    const float* W_in      = (const float*)d_in[1];
    const float* W_rec     = (const float*)d_in[2];
    const float* asc_amps  = (const float*)d_in[3];
    const float* k_decay   = (const float*)d_in[4];
    const float* W_out     = (const float*)d_in[5];
    const float* b_out     = (const float*)d_in[6];
    const float* in_scale  = (const float*)d_in[7];
    const float* out_scale = (const float*)d_in[8];
    float* out = (float*)d_out;

    if (ws_size >= WS_NEED) {
        float* gmaxa = (float*)((char*)d_ws + OFF_GMAXA);
        hipMemsetAsync(gmaxa, 0, GMAXA_N * sizeof(float), stream);  // capturable
        maxgemm_kernel<<<dim3(250, 4), 256, 0, stream>>>(x, W_in, in_scale, gmaxa);
        rsnn_seq_kernel<<<BATCH, 256, 0, stream>>>(
            gmaxa, x, W_in, W_rec, asc_amps, k_decay, W_out, b_out,
            in_scale, out_scale, out);
    } else {
        rsnn_seq_kernel<<<BATCH, 256, 0, stream>>>(
            nullptr, x, W_in, W_rec, asc_amps, k_decay, W_out, b_out,
            in_scale, out_scale, out);
    }
}

// Round 12
// 104.219 us; speedup vs baseline: 1.5159x; 1.0806x over previous
//
#include <hip/hip_runtime.h>
#include <stdint.h>

#define T_STEPS  1000
#define BATCH    32
#define N_NEURON 1000
#define IN_DIM   128
#define OUT_DIM  20

typedef unsigned short ushort_t;
typedef unsigned long long ull_t;
using f32x4  = __attribute__((ext_vector_type(4))) float;
using bf16x8 = __attribute__((ext_vector_type(8))) short;

// fp32 -> bf16 (RTN-even)
static __device__ __forceinline__ ushort_t f2bf(float f) {
    unsigned u = __float_as_uint(f);
    return (ushort_t)((u + 0x7FFFu + ((u >> 16) & 1u)) >> 16);
}

// ws layout (bytes): 1000 per-block maxima. Every slot is rewritten by
// maxgemm on every launch -> no memset node needed (gate never reads >999).
#define OFF_GMAXA 0ull
#define GMAXA_N   1000
#define WS_NEED   (GMAXA_N * 4ull)

#define SIL_TH 14.5f   // spike needs w>=15; bf16-GEMM error ~0.06; actual max ~5.5

// ============================================================================
// Kernel 1: max-reduced bf16 MFMA GEMM — one plain store per block.
// Silence proof: w_t = a_v*w_{t-1} + (1-a_v)*I_t (w = v-V_RESET, w0=0) is a
// convex combination of {0, past I}: w_max <= max(0, max I). Spike <=> w>=15.
// gmax < 14.5 => no spike ever, any batch => out = b_out exactly.
//
// r11 post-mortem fix: with Bf[4][4] (96+ live VGPRs) the compiler allocated
// only 88 and REMATERIALIZED B from global inside the mt-loop (~1 GB L2
// re-reads ≈ 30+ µs; no scratch writes, so r10's WRITE counter hid it).
// v5: process n-tiles in TWO PAIRS -> live set ~70 VGPRs (B-pair 32 + Af 16
// + 2 accs 8) -> remat structurally impossible. Extra cost: 2x ds_read_b128
// (64/wave, ~0.3 µs/block) + one more B-load latency. x slab in bf16 LDS
// (stride 132 shorts: <=2-way aliasing = free).
// ============================================================================
__global__ __launch_bounds__(256, 1) void maxgemm_kernel(
    const float* __restrict__ x, const float* __restrict__ W,
    const float* __restrict__ in_scale_p, float* __restrict__ gmaxa)
{
    __shared__ ushort_t xs[128 * 132];   // 33792 B
    __shared__ float wred[4];
    const int tid  = threadIdx.x;
    const int lane = tid & 63;
    const int wave = tid >> 6;
    const int quad = lane >> 4;
    const int l15  = lane & 15;
    const int m0   = blockIdx.x * 128;               // 250 * 128 = 32000 rows
    const int nbase = blockIdx.y * 256 + wave * 64;  // wave's 64 padded neurons
    const float is = in_scale_p[0];

    // ---- stage x[m0..m0+127][:] -> bf16 LDS (coalesced, conflict-free) ----
#pragma unroll
    for (int it = 0; it < 16; ++it) {
        int idx = tid + it * 256;        // 0..4095 = 128 rows x 32 float4
        int row = idx >> 5, c4 = idx & 31;
        float4 v = *(const float4*)(x + (size_t)(m0 + row) * IN_DIM + c4 * 4);
        ushort_t* p = xs + row * 132 + c4 * 4;
        *(ushort4*)p = make_ushort4(f2bf(v.x), f2bf(v.y), f2bf(v.z), f2bf(v.w));
    }
    __syncthreads();

    float mx = 0.f;    // clamped >= 0 (bound uses max(0, I))

#pragma unroll
    for (int h = 0; h < 2; ++h) {        // two pairs of 16-neuron tiles
        // ---- B-pair: fp32 W -> bf16 regs (32 VGPRs live) ----
        bf16x8 Bf[2][4];
#pragma unroll
        for (int p = 0; p < 2; ++p) {
            const int row = nbase + (h * 2 + p) * 16 + l15;
            const bool ok = row < N_NEURON;
            const float* wp = W + (size_t)row * IN_DIM;
#pragma unroll
            for (int kb = 0; kb < 4; ++kb) {
                float4 lo = ok ? *(const float4*)(wp + kb * 32 + quad * 8)
                               : make_float4(0.f, 0.f, 0.f, 0.f);
                float4 hi = ok ? *(const float4*)(wp + kb * 32 + quad * 8 + 4)
                               : make_float4(0.f, 0.f, 0.f, 0.f);
                bf16x8 f;
                f[0] = (short)f2bf(lo.x); f[1] = (short)f2bf(lo.y);
                f[2] = (short)f2bf(lo.z); f[3] = (short)f2bf(lo.w);
                f[4] = (short)f2bf(hi.x); f[5] = (short)f2bf(hi.y);
                f[6] = (short)f2bf(hi.z); f[7] = (short)f2bf(hi.w);
                Bf[p][kb] = f;
            }
        }

        // ---- 8 m-tiles x (2 n-tiles x 4 k-blocks) MFMAs -> max ----
#pragma unroll
        for (int mt = 0; mt < 8; ++mt) {
            bf16x8 Af[4];
#pragma unroll
            for (int kb = 0; kb < 4; ++kb)
                Af[kb] = *(const bf16x8*)(xs + (mt * 16 + l15) * 132 +
                                          kb * 32 + quad * 8);
            f32x4 a0 = (f32x4){0.f, 0.f, 0.f, 0.f};
            f32x4 a1 = (f32x4){0.f, 0.f, 0.f, 0.f};
#pragma unroll
            for (int kb = 0; kb < 4; ++kb) {
                a0 = __builtin_amdgcn_mfma_f32_16x16x32_bf16(Af[kb], Bf[0][kb], a0, 0, 0, 0);
                a1 = __builtin_amdgcn_mfma_f32_16x16x32_bf16(Af[kb], Bf[1][kb], a1, 0, 0, 0);
            }
#pragma unroll
            for (int i = 0; i < 4; ++i) {
                mx = fmaxf(mx, is * a0[i]);
                mx = fmaxf(mx, is * a1[i]);
            }
        }
    }

    // ---- lanes -> wave -> block (LDS) -> ONE plain store, no atomics ----
#pragma unroll
    for (int off = 32; off > 0; off >>= 1)
        mx = fmaxf(mx, __shfl_xor(mx, off, 64));
    if (lane == 0) wred[wave] = mx;
    __syncthreads();
    if (tid == 0) {
        float bm = fmaxf(fmaxf(wred[0], wred[1]), fmaxf(wred[2], wred[3]));
        gmaxa[blockIdx.y * 250 + blockIdx.x] = bm;   // slots 0..999, all written
    }
}

// ============================================================================
// Kernel 2: gated full sequential sim (round-1 structure, known correct),
// with the resolve folded in: each block scans the 1000 per-block maxima
// (bounds-checked -> never reads unwritten/poisoned slots); if silence is
// proven, write out = b_out bitwise and exit. gmaxa == nullptr -> always run.
// ============================================================================
__global__ __launch_bounds__(256) void rsnn_seq_kernel(
    const float* __restrict__ gmaxa,
    const float* __restrict__ x,
    const float* __restrict__ W_in,
    const float* __restrict__ W_rec,
    const float* __restrict__ asc_amps,
    const float* __restrict__ k_decay,
    const float* __restrict__ W_out,
    const float* __restrict__ b_out,
    const float* __restrict__ in_scale_p,
    const float* __restrict__ out_scale_p,
    float* __restrict__ out)
{
    const int b   = blockIdx.x;
    const int tid = threadIdx.x;

    if (gmaxa) {
        bool trig = false;
#pragma unroll
        for (int j = 0; j < 4; ++j) {
            int idx = tid * 4 + j;                  // 0..1023
            if (idx < GMAXA_N) trig |= (gmaxa[idx] >= SIL_TH);
        }
        int any = __syncthreads_or(trig ? 1 : 0);   // block-uniform
        if (any == 0) {                             // silence proven
            if (tid < OUT_DIM) out[b * OUT_DIM + tid] = b_out[tid];
            return;
        }
    }

    const int lane = tid & 63;
    const int wave = tid >> 6;
    const bool active = tid < (N_NEURON / 4);
    const int n0 = tid * 4;

    __shared__ ull_t smask[2][16];
    __shared__ float acc_sh[N_NEURON];
    __shared__ float xr[2][IN_DIM];

    const float a_v      = expf(-1.0f / 20.0f);
    const float a_syn    = expf(-1.0f / 5.0f);
    const float a_read   = expf(-1.0f / 20.0f);
    const float one_m_av = 1.0f - a_v;
    const float one_m_ar = 1.0f - a_read;
    const float VR = -60.0f, VTH = -45.0f;
    const float in_scale  = in_scale_p[0];
    const float out_scale = out_scale_p[0];

    float v[4], Ia[4], psc[4], f[4], acc[4], aasc[4], amp[4];
#pragma unroll
    for (int c = 0; c < 4; ++c) {
        v[c] = VR; Ia[c] = 0.f; psc[c] = 0.f; f[c] = 0.f; acc[c] = 0.f;
        aasc[c] = active ? expf(-k_decay[n0 + c]) : 0.f;
        amp[c]  = active ? asc_amps[n0 + c] : 0.f;
    }
    if (tid < 16) { smask[0][tid] = 0ull; smask[1][tid] = 0ull; }

    if (tid < IN_DIM / 4) {
        float4 xv = ((const float4*)(x + (size_t)b * IN_DIM))[tid];
        xr[0][tid * 4 + 0] = xv.x * in_scale; xr[0][tid * 4 + 1] = xv.y * in_scale;
        xr[0][tid * 4 + 2] = xv.z * in_scale; xr[0][tid * 4 + 3] = xv.w * in_scale;
    }
    int prev_any = 0;
    __syncthreads();

    for (int t = 0; t < T_STEPS; ++t) {
        const int cur = t & 1, nxt = cur ^ 1;
        if (t + 1 < T_STEPS && tid < IN_DIM / 4) {
            float4 xv = ((const float4*)(x + (size_t)((t + 1) * BATCH + b) * IN_DIM))[tid];
            xr[nxt][tid * 4 + 0] = xv.x * in_scale; xr[nxt][tid * 4 + 1] = xv.y * in_scale;
            xr[nxt][tid * 4 + 2] = xv.z * in_scale; xr[nxt][tid * 4 + 3] = xv.w * in_scale;
        }
        float4 Icur = make_float4(0.f, 0.f, 0.f, 0.f);
        if (active) {
            float s0 = 0.f, s1 = 0.f, s2 = 0.f, s3 = 0.f;
            const float4* w0 = (const float4*)(W_in + (size_t)(n0 + 0) * IN_DIM);
            const float4* w1 = (const float4*)(W_in + (size_t)(n0 + 1) * IN_DIM);
            const float4* w2 = (const float4*)(W_in + (size_t)(n0 + 2) * IN_DIM);
            const float4* w3 = (const float4*)(W_in + (size_t)(n0 + 3) * IN_DIM);
#pragma unroll 8
            for (int k4 = 0; k4 < IN_DIM / 4; ++k4) {
                float4 xv = *((const float4*)&xr[cur][0] + k4);
                float4 a0 = w0[k4], a1 = w1[k4], a2 = w2[k4], a3 = w3[k4];
                s0 += xv.x * a0.x + xv.y * a0.y + xv.z * a0.z + xv.w * a0.w;
                s1 += xv.x * a1.x + xv.y * a1.y + xv.z * a1.z + xv.w * a1.w;
                s2 += xv.x * a2.x + xv.y * a2.y + xv.z * a2.z + xv.w * a2.w;
                s3 += xv.x * a3.x + xv.y * a3.y + xv.z * a3.z + xv.w * a3.w;
            }
            Icur = make_float4(s0, s1, s2, s3);
        }

#pragma unroll
        for (int c = 0; c < 4; ++c) psc[c] *= a_syn;
        if (prev_any && active) {
#pragma unroll 1
            for (int w = 0; w < 16; ++w) {
                ull_t m = smask[nxt][w];
                while (m) {
                    int bit = __ffsll(m) - 1;
                    m &= m - 1;
                    int npre = ((w >> 2) << 8) + (bit << 2) + (w & 3);
                    const float4 wr = *(const float4*)(W_rec + (size_t)npre * N_NEURON + n0);
                    psc[0] += wr.x; psc[1] += wr.y; psc[2] += wr.z; psc[3] += wr.w;
                }
            }
        }

        float Iv[4] = {Icur.x, Icur.y, Icur.z, Icur.w};
        bool sp[4];
#pragma unroll
        for (int c = 0; c < 4; ++c) {
            float It = Iv[c] + psc[c] + Ia[c];
            float vn = VR + a_v * (v[c] - VR) + one_m_av * It;
            bool s = active && (vn - VTH >= 0.0f);
            float sf = s ? 1.0f : 0.0f;
            vn = vn - (vn - VR) * sf;
            v[c] = vn;
            Ia[c] = aasc[c] * Ia[c] + amp[c] * sf;
            f[c] = (t == 0) ? sf : (a_read * f[c] + one_m_ar * sf);
            if (t >= 199) acc[c] += f[c];
            sp[c] = s;
        }

#pragma unroll
        for (int c = 0; c < 4; ++c) {
            ull_t m = __ballot(sp[c]);
            if (lane == 0) smask[cur][wave * 4 + c] = m;
        }
        int myany = (sp[0] | sp[1] | sp[2] | sp[3]) ? 1 : 0;
        prev_any = __syncthreads_or(myany);
    }

    if (active) {
        acc_sh[n0 + 0] = acc[0]; acc_sh[n0 + 1] = acc[1];
        acc_sh[n0 + 2] = acc[2]; acc_sh[n0 + 3] = acc[3];
    }
    __syncthreads();

    const float inv_cnt = 1.0f / 801.0f;
#pragma unroll
    for (int oo = 0; oo < 5; ++oo) {
        int o = wave * 5 + oo;
        float p = 0.f;
        for (int n = lane; n < N_NEURON; n += 64)
            p += acc_sh[n] * W_out[(size_t)o * N_NEURON + n];
#pragma unroll
        for (int off = 32; off > 0; off >>= 1)
            p += __shfl_down(p, off, 64);
        if (lane == 0)
            out[b * OUT_DIM + o] = out_scale * (p * inv_cnt) + b_out[o];
    }
}

// ============================================================================
extern "C" void kernel_launch(void* const* d_in, const int* in_sizes, int n_in,
                              void* d_out, int out_size, void* d_ws, size_t ws_size,
                              hipStream_t stream)
{
    const float* x         = (const float*)d_in[0];
    const float* W_in      = (const float*)d_in[1];
    const float* W_rec     = (const float*)d_in[2];
    const float* asc_amps  = (const float*)d_in[3];
    const float* k_decay   = (const float*)d_in[4];
    const float* W_out     = (const float*)d_in[5];
    const float* b_out     = (const float*)d_in[6];
    const float* in_scale  = (const float*)d_in[7];
    const float* out_scale = (const float*)d_in[8];
    float* out = (float*)d_out;

    if (ws_size >= WS_NEED) {
        float* gmaxa = (float*)((char*)d_ws + OFF_GMAXA);
        maxgemm_kernel<<<dim3(250, 4), 256, 0, stream>>>(x, W_in, in_scale, gmaxa);
        rsnn_seq_kernel<<<BATCH, 256, 0, stream>>>(
            gmaxa, x, W_in, W_rec, asc_amps, k_decay, W_out, b_out,
            in_scale, out_scale, out);
    } else {
        rsnn_seq_kernel<<<BATCH, 256, 0, stream>>>(
            nullptr, x, W_in, W_rec, asc_amps, k_decay, W_out, b_out,
            in_scale, out_scale, out);
    }
}

// Round 13
// 98.194 us; speedup vs baseline: 1.6089x; 1.0614x over previous
//
#include <hip/hip_runtime.h>
#include <stdint.h>

#define T_STEPS  1000
#define BATCH    32
#define N_NEURON 1000
#define IN_DIM   128
#define OUT_DIM  20

typedef unsigned short ushort_t;
typedef unsigned long long ull_t;
using f32x4  = __attribute__((ext_vector_type(4))) float;
using bf16x8 = __attribute__((ext_vector_type(8))) short;

// fp32 -> bf16 (RTN-even)
static __device__ __forceinline__ ushort_t f2bf(float f) {
    unsigned u = __float_as_uint(f);
    return (ushort_t)((u + 0x7FFFu + ((u >> 16) & 1u)) >> 16);
}

// ws layout (bytes): 250 per-block maxima, ALL rewritten every launch
// (no memset node; gate only reads slots 0..249).
#define OFF_GMAXA 0ull
#define GMAXA_N   250
#define WS_NEED   (GMAXA_N * 4ull)

#define SIL_TH 14.5f   // spike needs w>=15; bf16-GEMM error ~0.06; actual max ~5.5

// ============================================================================
// Kernel 1: max-reduced bf16 MFMA GEMM — one plain store per block.
// Silence proof: w_t = a_v*w_{t-1} + (1-a_v)*I_t (w = v-V_RESET, w0=0) is a
// convex combination of {0, past I}: w_max <= max(0, max I). Spike <=> w>=15.
// gmax < 14.5 => no spike ever, any batch => out = b_out exactly.
//
// r12 post-mortem fix: grid (250,4) fetched x 4x (65 MB) and W per column —
// fetch-bound on redundant traffic (~25-30 µs). v6: grid = 250 blocks, ONE
// block covers all 1024 padded neurons; wave w owns [w*256, w*256+256) as
// 8 B-PAIRS (anti-remat live set ~70 VGPRs: B-pair 32 + Af 16 + accs 8,
// proven in r12). x staged once per block -> x fetched exactly once
// (16.4 MB); W (512 KB) is L2-resident across 250 blocks. x slab in bf16
// LDS stride 132 shorts (<=2-way aliasing = free).
// ============================================================================
__global__ __launch_bounds__(256, 1) void maxgemm_kernel(
    const float* __restrict__ x, const float* __restrict__ W,
    const float* __restrict__ in_scale_p, float* __restrict__ gmaxa)
{
    __shared__ ushort_t xs[128 * 132];   // 33792 B
    __shared__ float wred[4];
    const int tid  = threadIdx.x;
    const int lane = tid & 63;
    const int wave = tid >> 6;
    const int quad = lane >> 4;
    const int l15  = lane & 15;
    const int m0   = blockIdx.x * 128;   // 250 * 128 = 32000 rows exactly
    const int nwbase = wave * 256;       // wave's 256 padded neurons
    const float is = in_scale_p[0];

    // ---- stage x[m0..m0+127][:] -> bf16 LDS (coalesced, conflict-free) ----
#pragma unroll
    for (int it = 0; it < 16; ++it) {
        int idx = tid + it * 256;        // 0..4095 = 128 rows x 32 float4
        int row = idx >> 5, c4 = idx & 31;
        float4 v = *(const float4*)(x + (size_t)(m0 + row) * IN_DIM + c4 * 4);
        ushort_t* p = xs + row * 132 + c4 * 4;
        *(ushort4*)p = make_ushort4(f2bf(v.x), f2bf(v.y), f2bf(v.z), f2bf(v.w));
    }
    __syncthreads();

    float mx = 0.f;    // clamped >= 0 (bound uses max(0, I))

#pragma unroll 1
    for (int pp = 0; pp < 8; ++pp) {     // 8 pairs of 16-neuron tiles
        // ---- B-pair: fp32 W (L2-resident) -> bf16 regs (32 VGPRs live) ----
        bf16x8 Bf[2][4];
#pragma unroll
        for (int p = 0; p < 2; ++p) {
            const int row = nwbase + pp * 32 + p * 16 + l15;
            const bool ok = row < N_NEURON;
            const float* wp = W + (size_t)row * IN_DIM;
#pragma unroll
            for (int kb = 0; kb < 4; ++kb) {
                float4 lo = ok ? *(const float4*)(wp + kb * 32 + quad * 8)
                               : make_float4(0.f, 0.f, 0.f, 0.f);
                float4 hi = ok ? *(const float4*)(wp + kb * 32 + quad * 8 + 4)
                               : make_float4(0.f, 0.f, 0.f, 0.f);
                bf16x8 f;
                f[0] = (short)f2bf(lo.x); f[1] = (short)f2bf(lo.y);
                f[2] = (short)f2bf(lo.z); f[3] = (short)f2bf(lo.w);
                f[4] = (short)f2bf(hi.x); f[5] = (short)f2bf(hi.y);
                f[6] = (short)f2bf(hi.z); f[7] = (short)f2bf(hi.w);
                Bf[p][kb] = f;
            }
        }

        // ---- 8 m-tiles x (2 n-tiles x 4 k-blocks) MFMAs -> max ----
#pragma unroll
        for (int mt = 0; mt < 8; ++mt) {
            bf16x8 Af[4];
#pragma unroll
            for (int kb = 0; kb < 4; ++kb)
                Af[kb] = *(const bf16x8*)(xs + (mt * 16 + l15) * 132 +
                                          kb * 32 + quad * 8);
            f32x4 a0 = (f32x4){0.f, 0.f, 0.f, 0.f};
            f32x4 a1 = (f32x4){0.f, 0.f, 0.f, 0.f};
#pragma unroll
            for (int kb = 0; kb < 4; ++kb) {
                a0 = __builtin_amdgcn_mfma_f32_16x16x32_bf16(Af[kb], Bf[0][kb], a0, 0, 0, 0);
                a1 = __builtin_amdgcn_mfma_f32_16x16x32_bf16(Af[kb], Bf[1][kb], a1, 0, 0, 0);
            }
#pragma unroll
            for (int i = 0; i < 4; ++i) {
                mx = fmaxf(mx, is * a0[i]);
                mx = fmaxf(mx, is * a1[i]);
            }
        }
    }

    // ---- lanes -> wave -> block (LDS) -> ONE plain store, no atomics ----
#pragma unroll
    for (int off = 32; off > 0; off >>= 1)
        mx = fmaxf(mx, __shfl_xor(mx, off, 64));
    if (lane == 0) wred[wave] = mx;
    __syncthreads();
    if (tid == 0) {
        float bm = fmaxf(fmaxf(wred[0], wred[1]), fmaxf(wred[2], wred[3]));
        gmaxa[blockIdx.x] = bm;          // slots 0..249, all written
    }
}

// ============================================================================
// Kernel 2: gated full sequential sim (round-1 structure, known correct),
// with the resolve folded in: each block scans the 250 per-block maxima
// (bounds-checked -> never reads unwritten/poisoned slots); if silence is
// proven, write out = b_out bitwise and exit. gmaxa == nullptr -> always run.
// ============================================================================
__global__ __launch_bounds__(256) void rsnn_seq_kernel(
    const float* __restrict__ gmaxa,
    const float* __restrict__ x,
    const float* __restrict__ W_in,
    const float* __restrict__ W_rec,
    const float* __restrict__ asc_amps,
    const float* __restrict__ k_decay,
    const float* __restrict__ W_out,
    const float* __restrict__ b_out,
    const float* __restrict__ in_scale_p,
    const float* __restrict__ out_scale_p,
    float* __restrict__ out)
{
    const int b   = blockIdx.x;
    const int tid = threadIdx.x;

    if (gmaxa) {
        bool trig = (tid < GMAXA_N) && (gmaxa[tid] >= SIL_TH);
        int any = __syncthreads_or(trig ? 1 : 0);   // block-uniform
        if (any == 0) {                             // silence proven
            if (tid < OUT_DIM) out[b * OUT_DIM + tid] = b_out[tid];
            return;
        }
    }

    const int lane = tid & 63;
    const int wave = tid >> 6;
    const bool active = tid < (N_NEURON / 4);
    const int n0 = tid * 4;

    __shared__ ull_t smask[2][16];
    __shared__ float acc_sh[N_NEURON];
    __shared__ float xr[2][IN_DIM];

    const float a_v      = expf(-1.0f / 20.0f);
    const float a_syn    = expf(-1.0f / 5.0f);
    const float a_read   = expf(-1.0f / 20.0f);
    const float one_m_av = 1.0f - a_v;
    const float one_m_ar = 1.0f - a_read;
    const float VR = -60.0f, VTH = -45.0f;
    const float in_scale  = in_scale_p[0];
    const float out_scale = out_scale_p[0];

    float v[4], Ia[4], psc[4], f[4], acc[4], aasc[4], amp[4];
#pragma unroll
    for (int c = 0; c < 4; ++c) {
        v[c] = VR; Ia[c] = 0.f; psc[c] = 0.f; f[c] = 0.f; acc[c] = 0.f;
        aasc[c] = active ? expf(-k_decay[n0 + c]) : 0.f;
        amp[c]  = active ? asc_amps[n0 + c] : 0.f;
    }
    if (tid < 16) { smask[0][tid] = 0ull; smask[1][tid] = 0ull; }

    if (tid < IN_DIM / 4) {
        float4 xv = ((const float4*)(x + (size_t)b * IN_DIM))[tid];
        xr[0][tid * 4 + 0] = xv.x * in_scale; xr[0][tid * 4 + 1] = xv.y * in_scale;
        xr[0][tid * 4 + 2] = xv.z * in_scale; xr[0][tid * 4 + 3] = xv.w * in_scale;
    }
    int prev_any = 0;
    __syncthreads();

    for (int t = 0; t < T_STEPS; ++t) {
        const int cur = t & 1, nxt = cur ^ 1;
        if (t + 1 < T_STEPS && tid < IN_DIM / 4) {
            float4 xv = ((const float4*)(x + (size_t)((t + 1) * BATCH + b) * IN_DIM))[tid];
            xr[nxt][tid * 4 + 0] = xv.x * in_scale; xr[nxt][tid * 4 + 1] = xv.y * in_scale;
            xr[nxt][tid * 4 + 2] = xv.z * in_scale; xr[nxt][tid * 4 + 3] = xv.w * in_scale;
        }
        float4 Icur = make_float4(0.f, 0.f, 0.f, 0.f);
        if (active) {
            float s0 = 0.f, s1 = 0.f, s2 = 0.f, s3 = 0.f;
            const float4* w0 = (const float4*)(W_in + (size_t)(n0 + 0) * IN_DIM);
            const float4* w1 = (const float4*)(W_in + (size_t)(n0 + 1) * IN_DIM);
            const float4* w2 = (const float4*)(W_in + (size_t)(n0 + 2) * IN_DIM);
            const float4* w3 = (const float4*)(W_in + (size_t)(n0 + 3) * IN_DIM);
#pragma unroll 8
            for (int k4 = 0; k4 < IN_DIM / 4; ++k4) {
                float4 xv = *((const float4*)&xr[cur][0] + k4);
                float4 a0 = w0[k4], a1 = w1[k4], a2 = w2[k4], a3 = w3[k4];
                s0 += xv.x * a0.x + xv.y * a0.y + xv.z * a0.z + xv.w * a0.w;
                s1 += xv.x * a1.x + xv.y * a1.y + xv.z * a1.z + xv.w * a1.w;
                s2 += xv.x * a2.x + xv.y * a2.y + xv.z * a2.z + xv.w * a2.w;
                s3 += xv.x * a3.x + xv.y * a3.y + xv.z * a3.z + xv.w * a3.w;
            }
            Icur = make_float4(s0, s1, s2, s3);
        }

#pragma unroll
        for (int c = 0; c < 4; ++c) psc[c] *= a_syn;
        if (prev_any && active) {
#pragma unroll 1
            for (int w = 0; w < 16; ++w) {
                ull_t m = smask[nxt][w];
                while (m) {
                    int bit = __ffsll(m) - 1;
                    m &= m - 1;
                    int npre = ((w >> 2) << 8) + (bit << 2) + (w & 3);
                    const float4 wr = *(const float4*)(W_rec + (size_t)npre * N_NEURON + n0);
                    psc[0] += wr.x; psc[1] += wr.y; psc[2] += wr.z; psc[3] += wr.w;
                }
            }
        }

        float Iv[4] = {Icur.x, Icur.y, Icur.z, Icur.w};
        bool sp[4];
#pragma unroll
        for (int c = 0; c < 4; ++c) {
            float It = Iv[c] + psc[c] + Ia[c];
            float vn = VR + a_v * (v[c] - VR) + one_m_av * It;
            bool s = active && (vn - VTH >= 0.0f);
            float sf = s ? 1.0f : 0.0f;
            vn = vn - (vn - VR) * sf;
            v[c] = vn;
            Ia[c] = aasc[c] * Ia[c] + amp[c] * sf;
            f[c] = (t == 0) ? sf : (a_read * f[c] + one_m_ar * sf);
            if (t >= 199) acc[c] += f[c];
            sp[c] = s;
        }

#pragma unroll
        for (int c = 0; c < 4; ++c) {
            ull_t m = __ballot(sp[c]);
            if (lane == 0) smask[cur][wave * 4 + c] = m;
        }
        int myany = (sp[0] | sp[1] | sp[2] | sp[3]) ? 1 : 0;
        prev_any = __syncthreads_or(myany);
    }

    if (active) {
        acc_sh[n0 + 0] = acc[0]; acc_sh[n0 + 1] = acc[1];
        acc_sh[n0 + 2] = acc[2]; acc_sh[n0 + 3] = acc[3];
    }
    __syncthreads();

    const float inv_cnt = 1.0f / 801.0f;
#pragma unroll
    for (int oo = 0; oo < 5; ++oo) {
        int o = wave * 5 + oo;
        float p = 0.f;
        for (int n = lane; n < N_NEURON; n += 64)
            p += acc_sh[n] * W_out[(size_t)o * N_NEURON + n];
#pragma unroll
        for (int off = 32; off > 0; off >>= 1)
            p += __shfl_down(p, off, 64);
        if (lane == 0)
            out[b * OUT_DIM + o] = out_scale * (p * inv_cnt) + b_out[o];
    }
}

// ============================================================================
extern "C" void kernel_launch(void* const* d_in, const int* in_sizes, int n_in,
                              void* d_out, int out_size, void* d_ws, size_t ws_size,
                              hipStream_t stream)
{
    const float* x         = (const float*)d_in[0];
    const float* W_in      = (const float*)d_in[1];
    const float* W_rec     = (const float*)d_in[2];
    const float* asc_amps  = (const float*)d_in[3];
    const float* k_decay   = (const float*)d_in[4];
    const float* W_out     = (const float*)d_in[5];
    const float* b_out     = (const float*)d_in[6];
    const float* in_scale  = (const float*)d_in[7];
    const float* out_scale = (const float*)d_in[8];
    float* out = (float*)d_out;

    if (ws_size >= WS_NEED) {
        float* gmaxa = (float*)((char*)d_ws + OFF_GMAXA);
        maxgemm_kernel<<<250, 256, 0, stream>>>(x, W_in, in_scale, gmaxa);
        rsnn_seq_kernel<<<BATCH, 256, 0, stream>>>(
            gmaxa, x, W_in, W_rec, asc_amps, k_decay, W_out, b_out,
            in_scale, out_scale, out);
    } else {
        rsnn_seq_kernel<<<BATCH, 256, 0, stream>>>(
            nullptr, x, W_in, W_rec, asc_amps, k_decay, W_out, b_out,
            in_scale, out_scale, out);
    }
}